// Round 1
// baseline (737.922 us; speedup 1.0000x reference)
//
#include <hip/hip_runtime.h>

#define N_NODES 10000
#define EMB 10

// workspace float offsets
#define WS_SEDGE 0            // [16] edge-embedding sums (atomic, zeroed)
#define WS_CBASE 16           // [16] ws_b + v_weights
#define WS_SSUM  32           // [16] column sums of emb3 (atomic, zeroed)
#define WS_QVEC  48           // [10] folded wqact_w @ wqr_w[10:20]; qc at +10
#define WS_EMBA  64
#define WS_EMBTA (64 + 100000)
#define WS_EMBB  (64 + 200000)
#define WS_EMBTB (64 + 300000)

// ---- K1: sum_e relu(w_e * wew_w[j] + wew_b[j]) -> sEdge[j] ----
__global__ void k_edge_sum(const float* __restrict__ w, int E,
                           const float* __restrict__ wew_w,
                           const float* __restrict__ wew_b,
                           float* __restrict__ sEdge) {
    __shared__ float red[4][EMB];
    float a[EMB], b[EMB], acc[EMB];
#pragma unroll
    for (int j = 0; j < EMB; ++j) { a[j] = wew_w[j]; b[j] = wew_b[j]; acc[j] = 0.f; }
    for (int e = blockIdx.x * blockDim.x + threadIdx.x; e < E; e += gridDim.x * blockDim.x) {
        float we = w[e];
#pragma unroll
        for (int j = 0; j < EMB; ++j) acc[j] += fmaxf(we * a[j] + b[j], 0.f);
    }
#pragma unroll
    for (int m = 1; m < 64; m <<= 1)
#pragma unroll
        for (int j = 0; j < EMB; ++j) acc[j] += __shfl_xor(acc[j], m, 64);
    int wave = threadIdx.x >> 6, lane = threadIdx.x & 63;
    if (lane == 0)
#pragma unroll
        for (int j = 0; j < EMB; ++j) red[wave][j] = acc[j];
    __syncthreads();
    if (threadIdx.x < EMB)
        atomicAdd(&sEdge[threadIdx.x],
                  red[0][threadIdx.x] + red[1][threadIdx.x] + red[2][threadIdx.x] + red[3][threadIdx.x]);
}

// ---- K2: cbase[j] = ws_b[j] + (sEdge @ wnw_w + wnw_b)[j] ----
__global__ void k_prep1(const float* __restrict__ sEdge, const float* __restrict__ wnw_w,
                        const float* __restrict__ wnw_b, const float* __restrict__ ws_b,
                        float* __restrict__ cbase) {
    int j = threadIdx.x;
    if (j < EMB) {
        float v = wnw_b[j];
        for (int k = 0; k < EMB; ++k) v += sEdge[k] * wnw_w[k * EMB + j];
        cbase[j] = v + ws_b[j];
    }
}

// ---- K3: emb1 (iter 1 closed form, since A@0 == 0) ----
__global__ void k_emb1(const float* __restrict__ f, const float* __restrict__ ws_w,
                       const float* __restrict__ cbase, const float* __restrict__ wnp_b,
                       float* __restrict__ emb, float* __restrict__ embT) {
    int i = blockIdx.x * blockDim.x + threadIdx.x;
    if (i < N_NODES) {
        float fi = f[i];
#pragma unroll
        for (int j = 0; j < EMB; ++j) {
            float v = fmaxf(fi * ws_w[j] + cbase[j] + wnp_b[j], 0.f);
            emb[(size_t)i * EMB + j] = v;
            embT[(size_t)j * N_NODES + i] = v;
        }
    }
}

// ---- K4: fused y = A@emb ; emb' = relu(f*ws_w + cbase + y@wnp_w + wnp_b) ----
// block = 256 (4 waves), wave handles 4 rows; lane handles float4 column chunks.
__global__ __launch_bounds__(256) void k_iter(
    const float* __restrict__ A, const float* __restrict__ embT_in,
    const float* __restrict__ f, const float* __restrict__ ws_w,
    const float* __restrict__ cbase, const float* __restrict__ wnp_w,
    const float* __restrict__ wnp_b,
    float* __restrict__ emb_out, float* __restrict__ embT_out) {
    const int wave = threadIdx.x >> 6;
    const int lane = threadIdx.x & 63;
    const int r0 = blockIdx.x * 16 + wave * 4;

    float acc[4][EMB];
#pragma unroll
    for (int r = 0; r < 4; ++r)
#pragma unroll
        for (int j = 0; j < EMB; ++j) acc[r][j] = 0.f;

    const float4* A0 = (const float4*)(A + (size_t)(r0 + 0) * N_NODES);
    const float4* A1 = (const float4*)(A + (size_t)(r0 + 1) * N_NODES);
    const float4* A2 = (const float4*)(A + (size_t)(r0 + 2) * N_NODES);
    const float4* A3 = (const float4*)(A + (size_t)(r0 + 3) * N_NODES);

    const int NSTEP = N_NODES / 256;  // 39 full 256-column steps
    int c4 = lane;
#pragma unroll 2
    for (int s = 0; s < NSTEP; ++s, c4 += 64) {
        float4 a0 = A0[c4], a1 = A1[c4], a2 = A2[c4], a3 = A3[c4];
#pragma unroll
        for (int j = 0; j < EMB; ++j) {
            float4 e = ((const float4*)(embT_in + (size_t)j * N_NODES))[c4];
            acc[0][j] += a0.x * e.x + a0.y * e.y + a0.z * e.z + a0.w * e.w;
            acc[1][j] += a1.x * e.x + a1.y * e.y + a1.z * e.z + a1.w * e.w;
            acc[2][j] += a2.x * e.x + a2.y * e.y + a2.z * e.z + a2.w * e.w;
            acc[3][j] += a3.x * e.x + a3.y * e.y + a3.z * e.z + a3.w * e.w;
        }
    }
    // tail: 10000 % 256 = 16 columns -> 4 float4s, lanes 0..3
    if (lane < (N_NODES % 256) / 4) {
        int ct = NSTEP * 64 + lane;
        float4 a0 = A0[ct], a1 = A1[ct], a2 = A2[ct], a3 = A3[ct];
#pragma unroll
        for (int j = 0; j < EMB; ++j) {
            float4 e = ((const float4*)(embT_in + (size_t)j * N_NODES))[ct];
            acc[0][j] += a0.x * e.x + a0.y * e.y + a0.z * e.z + a0.w * e.w;
            acc[1][j] += a1.x * e.x + a1.y * e.y + a1.z * e.z + a1.w * e.w;
            acc[2][j] += a2.x * e.x + a2.y * e.y + a2.z * e.z + a2.w * e.w;
            acc[3][j] += a3.x * e.x + a3.y * e.y + a3.z * e.z + a3.w * e.w;
        }
    }

    // 64-lane butterfly: afterwards every lane holds full sums
#pragma unroll
    for (int m = 1; m < 64; m <<= 1)
#pragma unroll
        for (int r = 0; r < 4; ++r)
#pragma unroll
            for (int j = 0; j < EMB; ++j) acc[r][j] += __shfl_xor(acc[r][j], m, 64);

    if (lane < 4) {
        // static-select our row's accumulators (avoid runtime-indexed reg array)
        float myacc[EMB];
#pragma unroll
        for (int k = 0; k < EMB; ++k)
            myacc[k] = lane == 0 ? acc[0][k]
                     : lane == 1 ? acc[1][k]
                     : lane == 2 ? acc[2][k]
                                 : acc[3][k];
        int i = r0 + lane;
        float fi = f[i];
#pragma unroll
        for (int j = 0; j < EMB; ++j) {
            float v = wnp_b[j];
#pragma unroll
            for (int k = 0; k < EMB; ++k) v += myacc[k] * wnp_w[k * EMB + j];
            v = fmaxf(fi * ws_w[j] + cbase[j] + v, 0.f);
            emb_out[(size_t)i * EMB + j] = v;
            embT_out[(size_t)j * N_NODES + i] = v;
        }
    }
}

// ---- K5: ssum[j] = sum_i emb3[i][j], reading transposed layout ----
__global__ void k_colsum(const float* __restrict__ embT, float* __restrict__ ssum) {
    int j = blockIdx.x % EMB;
    int s = blockIdx.x / EMB;  // 8 stripes with 80 blocks
    float acc = 0.f;
    for (int i = s * blockDim.x + threadIdx.x; i < N_NODES; i += (gridDim.x / EMB) * blockDim.x)
        acc += embT[(size_t)j * N_NODES + i];
#pragma unroll
    for (int m = 1; m < 64; m <<= 1) acc += __shfl_xor(acc, m, 64);
    __shared__ float red[4];
    int wave = threadIdx.x >> 6, lane = threadIdx.x & 63;
    if (lane == 0) red[wave] = acc;
    __syncthreads();
    if (threadIdx.x == 0) atomicAdd(&ssum[j], red[0] + red[1] + red[2] + red[3]);
}

// ---- K6: fold all trailing linears into qvec[10] + scalar qc ----
// q[i] = qc + emb3[i][:] . qvec
__global__ void k_prep2(const float* __restrict__ ssum, const float* __restrict__ wqa_w,
                        const float* __restrict__ wqa_b, const float* __restrict__ wqr_w,
                        const float* __restrict__ wqr_b, const float* __restrict__ wqact_w,
                        const float* __restrict__ wqact_b,
                        float* __restrict__ qvec, float* __restrict__ qc) {
    int t = threadIdx.x;
    float contrib = 0.f;
    if (t < EMB) {
        float se = wqa_b[t];
        for (int k = 0; k < EMB; ++k) se += ssum[k] * wqa_w[k * EMB + t];
        contrib = se * wqr_w[t] + wqact_b[t] * wqr_w[EMB + t];
        float qv = 0.f;
        for (int j = 0; j < EMB; ++j) qv += wqact_w[t * EMB + j] * wqr_w[EMB + j];
        qvec[t] = qv;
    }
#pragma unroll
    for (int m = 1; m < 64; m <<= 1) contrib += __shfl_xor(contrib, m, 64);
    if (t == 0) qc[0] = contrib + wqr_b[0];
}

// ---- K7: q_vals + copy embeddings to output ----
__global__ void k_out(const float* __restrict__ emb, const float* __restrict__ qvec,
                      const float* __restrict__ qc, float* __restrict__ out) {
    int i = blockIdx.x * blockDim.x + threadIdx.x;
    if (i < N_NODES) {
        float q = qc[0];
        float row[EMB];
#pragma unroll
        for (int j = 0; j < EMB; ++j) {
            row[j] = emb[(size_t)i * EMB + j];
            q += row[j] * qvec[j];
        }
        out[i] = q;
#pragma unroll
        for (int j = 0; j < EMB; ++j) out[N_NODES + (size_t)i * EMB + j] = row[j];
    }
}

extern "C" void kernel_launch(void* const* d_in, const int* in_sizes, int n_in,
                              void* d_out, int out_size, void* d_ws, size_t ws_size,
                              hipStream_t stream) {
    (void)n_in; (void)out_size; (void)ws_size;
    const float* f      = (const float*)d_in[0];
    const float* w      = (const float*)d_in[1];
    const float* A      = (const float*)d_in[2];
    const float* ws_w   = (const float*)d_in[3];
    const float* ws_b   = (const float*)d_in[4];
    const float* wnp_w  = (const float*)d_in[5];
    const float* wnp_b  = (const float*)d_in[6];
    const float* wnw_w  = (const float*)d_in[7];
    const float* wnw_b  = (const float*)d_in[8];
    const float* wew_w  = (const float*)d_in[9];
    const float* wew_b  = (const float*)d_in[10];
    const float* wqr_w  = (const float*)d_in[11];
    const float* wqr_b  = (const float*)d_in[12];
    const float* wqa_w  = (const float*)d_in[13];
    const float* wqa_b  = (const float*)d_in[14];
    const float* wqact_w = (const float*)d_in[15];
    const float* wqact_b = (const float*)d_in[16];
    float* ws  = (float*)d_ws;
    float* out = (float*)d_out;
    const int E = in_sizes[1];

    hipMemsetAsync(ws, 0, 64 * sizeof(float), stream);
    k_edge_sum<<<64, 256, 0, stream>>>(w, E, wew_w, wew_b, ws + WS_SEDGE);
    k_prep1<<<1, 64, 0, stream>>>(ws + WS_SEDGE, wnw_w, wnw_b, ws_b, ws + WS_CBASE);
    k_emb1<<<(N_NODES + 255) / 256, 256, 0, stream>>>(f, ws_w, ws + WS_CBASE, wnp_b,
                                                      ws + WS_EMBA, ws + WS_EMBTA);
    // iter 2: embA -> embB
    k_iter<<<N_NODES / 16, 256, 0, stream>>>(A, ws + WS_EMBTA, f, ws_w, ws + WS_CBASE,
                                             wnp_w, wnp_b, ws + WS_EMBB, ws + WS_EMBTB);
    // iter 3: embB -> embA
    k_iter<<<N_NODES / 16, 256, 0, stream>>>(A, ws + WS_EMBTB, f, ws_w, ws + WS_CBASE,
                                             wnp_w, wnp_b, ws + WS_EMBA, ws + WS_EMBTA);
    k_colsum<<<80, 256, 0, stream>>>(ws + WS_EMBTA, ws + WS_SSUM);
    k_prep2<<<1, 64, 0, stream>>>(ws + WS_SSUM, wqa_w, wqa_b, wqr_w, wqr_b,
                                  wqact_w, wqact_b, ws + WS_QVEC, ws + WS_QVEC + 10);
    k_out<<<(N_NODES + 255) / 256, 256, 0, stream>>>(ws + WS_EMBA, ws + WS_QVEC,
                                                     ws + WS_QVEC + 10, out);
}

// Round 2
// 726.144 us; speedup vs baseline: 1.0162x; 1.0162x over previous
//
#include <hip/hip_runtime.h>

#define N_NODES 10000
#define EMB 10

typedef float f32x4 __attribute__((ext_vector_type(4)));

// workspace float offsets
#define WS_SEDGE 0            // [16] edge-embedding sums (atomic, zeroed)
#define WS_CBASE 16           // [16] ws_b + v_weights
#define WS_SSUM  32           // [16] column sums of emb3 (atomic, zeroed)
#define WS_QVEC  48           // [10] folded wqact_w @ wqr_w[10:20]; qc at +10
#define WS_EMBA  64
#define WS_EMBTA (64 + 100000)
#define WS_EMBB  (64 + 200000)
#define WS_EMBTB (64 + 300000)

// ---- K1: sum_e relu(w_e * wew_w[j] + wew_b[j]) -> sEdge[j] ----
__global__ void k_edge_sum(const float* __restrict__ w, int E,
                           const float* __restrict__ wew_w,
                           const float* __restrict__ wew_b,
                           float* __restrict__ sEdge) {
    __shared__ float red[4][EMB];
    float a[EMB], b[EMB], acc[EMB];
#pragma unroll
    for (int j = 0; j < EMB; ++j) { a[j] = wew_w[j]; b[j] = wew_b[j]; acc[j] = 0.f; }
    for (int e = blockIdx.x * blockDim.x + threadIdx.x; e < E; e += gridDim.x * blockDim.x) {
        float we = w[e];
#pragma unroll
        for (int j = 0; j < EMB; ++j) acc[j] += fmaxf(we * a[j] + b[j], 0.f);
    }
#pragma unroll
    for (int m = 1; m < 64; m <<= 1)
#pragma unroll
        for (int j = 0; j < EMB; ++j) acc[j] += __shfl_xor(acc[j], m, 64);
    int wave = threadIdx.x >> 6, lane = threadIdx.x & 63;
    if (lane == 0)
#pragma unroll
        for (int j = 0; j < EMB; ++j) red[wave][j] = acc[j];
    __syncthreads();
    if (threadIdx.x < EMB)
        atomicAdd(&sEdge[threadIdx.x],
                  red[0][threadIdx.x] + red[1][threadIdx.x] + red[2][threadIdx.x] + red[3][threadIdx.x]);
}

// ---- K2: cbase[j] = ws_b[j] + (sEdge @ wnw_w + wnw_b)[j] ----
__global__ void k_prep1(const float* __restrict__ sEdge, const float* __restrict__ wnw_w,
                        const float* __restrict__ wnw_b, const float* __restrict__ ws_b,
                        float* __restrict__ cbase) {
    int j = threadIdx.x;
    if (j < EMB) {
        float v = wnw_b[j];
        for (int k = 0; k < EMB; ++k) v += sEdge[k] * wnw_w[k * EMB + j];
        cbase[j] = v + ws_b[j];
    }
}

// ---- K3: emb1 (iter 1 closed form, since A@0 == 0) ----
__global__ void k_emb1(const float* __restrict__ f, const float* __restrict__ ws_w,
                       const float* __restrict__ cbase, const float* __restrict__ wnp_b,
                       float* __restrict__ emb, float* __restrict__ embT) {
    int i = blockIdx.x * blockDim.x + threadIdx.x;
    if (i < N_NODES) {
        float fi = f[i];
#pragma unroll
        for (int j = 0; j < EMB; ++j) {
            float v = fmaxf(fi * ws_w[j] + cbase[j] + wnp_b[j], 0.f);
            emb[(size_t)i * EMB + j] = v;
            embT[(size_t)j * N_NODES + i] = v;
        }
    }
}

// ---- K4: fused y = A@emb ; emb' = relu(f*ws_w + cbase + y@wnp_w + wnp_b) ----
// block = 256 (4 waves), wave handles 4 rows; lane handles float4 column chunks.
// A is streamed once -> NON-TEMPORAL loads so the 400 KB embT stays L2-resident.
__global__ __launch_bounds__(256) void k_iter(
    const float* __restrict__ A, const float* __restrict__ embT_in,
    const float* __restrict__ f, const float* __restrict__ ws_w,
    const float* __restrict__ cbase, const float* __restrict__ wnp_w,
    const float* __restrict__ wnp_b,
    float* __restrict__ emb_out, float* __restrict__ embT_out) {
    const int wave = threadIdx.x >> 6;
    const int lane = threadIdx.x & 63;
    const int r0 = blockIdx.x * 16 + wave * 4;

    float acc[4][EMB];
#pragma unroll
    for (int r = 0; r < 4; ++r)
#pragma unroll
        for (int j = 0; j < EMB; ++j) acc[r][j] = 0.f;

    const f32x4* A0 = (const f32x4*)(A + (size_t)(r0 + 0) * N_NODES);
    const f32x4* A1 = (const f32x4*)(A + (size_t)(r0 + 1) * N_NODES);
    const f32x4* A2 = (const f32x4*)(A + (size_t)(r0 + 2) * N_NODES);
    const f32x4* A3 = (const f32x4*)(A + (size_t)(r0 + 3) * N_NODES);

    const int NSTEP = N_NODES / 256;  // 39 full 256-column steps
    int c4 = lane;
#pragma unroll 1
    for (int s = 0; s < NSTEP; ++s, c4 += 64) {
        f32x4 a0 = __builtin_nontemporal_load(A0 + c4);
        f32x4 a1 = __builtin_nontemporal_load(A1 + c4);
        f32x4 a2 = __builtin_nontemporal_load(A2 + c4);
        f32x4 a3 = __builtin_nontemporal_load(A3 + c4);
#pragma unroll
        for (int j = 0; j < EMB; ++j) {
            f32x4 e = ((const f32x4*)(embT_in + (size_t)j * N_NODES))[c4];
            acc[0][j] += a0.x * e.x + a0.y * e.y + a0.z * e.z + a0.w * e.w;
            acc[1][j] += a1.x * e.x + a1.y * e.y + a1.z * e.z + a1.w * e.w;
            acc[2][j] += a2.x * e.x + a2.y * e.y + a2.z * e.z + a2.w * e.w;
            acc[3][j] += a3.x * e.x + a3.y * e.y + a3.z * e.z + a3.w * e.w;
        }
    }
    // tail: 10000 % 256 = 16 columns -> 4 float4s, lanes 0..3
    if (lane < (N_NODES % 256) / 4) {
        int ct = NSTEP * 64 + lane;
        f32x4 a0 = __builtin_nontemporal_load(A0 + ct);
        f32x4 a1 = __builtin_nontemporal_load(A1 + ct);
        f32x4 a2 = __builtin_nontemporal_load(A2 + ct);
        f32x4 a3 = __builtin_nontemporal_load(A3 + ct);
#pragma unroll
        for (int j = 0; j < EMB; ++j) {
            f32x4 e = ((const f32x4*)(embT_in + (size_t)j * N_NODES))[ct];
            acc[0][j] += a0.x * e.x + a0.y * e.y + a0.z * e.z + a0.w * e.w;
            acc[1][j] += a1.x * e.x + a1.y * e.y + a1.z * e.z + a1.w * e.w;
            acc[2][j] += a2.x * e.x + a2.y * e.y + a2.z * e.z + a2.w * e.w;
            acc[3][j] += a3.x * e.x + a3.y * e.y + a3.z * e.z + a3.w * e.w;
        }
    }

    // 64-lane butterfly: afterwards every lane holds full sums
#pragma unroll
    for (int m = 1; m < 64; m <<= 1)
#pragma unroll
        for (int r = 0; r < 4; ++r)
#pragma unroll
            for (int j = 0; j < EMB; ++j) acc[r][j] += __shfl_xor(acc[r][j], m, 64);

    if (lane < 4) {
        // static-select our row's accumulators (avoid runtime-indexed reg array)
        float myacc[EMB];
#pragma unroll
        for (int k = 0; k < EMB; ++k)
            myacc[k] = lane == 0 ? acc[0][k]
                     : lane == 1 ? acc[1][k]
                     : lane == 2 ? acc[2][k]
                                 : acc[3][k];
        int i = r0 + lane;
        float fi = f[i];
#pragma unroll
        for (int j = 0; j < EMB; ++j) {
            float v = wnp_b[j];
#pragma unroll
            for (int k = 0; k < EMB; ++k) v += myacc[k] * wnp_w[k * EMB + j];
            v = fmaxf(fi * ws_w[j] + cbase[j] + v, 0.f);
            emb_out[(size_t)i * EMB + j] = v;
            embT_out[(size_t)j * N_NODES + i] = v;
        }
    }
}

// ---- K5: ssum[j] = sum_i emb3[i][j], reading transposed layout ----
__global__ void k_colsum(const float* __restrict__ embT, float* __restrict__ ssum) {
    int j = blockIdx.x % EMB;
    int s = blockIdx.x / EMB;  // 8 stripes with 80 blocks
    float acc = 0.f;
    for (int i = s * blockDim.x + threadIdx.x; i < N_NODES; i += (gridDim.x / EMB) * blockDim.x)
        acc += embT[(size_t)j * N_NODES + i];
#pragma unroll
    for (int m = 1; m < 64; m <<= 1) acc += __shfl_xor(acc, m, 64);
    __shared__ float red[4];
    int wave = threadIdx.x >> 6, lane = threadIdx.x & 63;
    if (lane == 0) red[wave] = acc;
    __syncthreads();
    if (threadIdx.x == 0) atomicAdd(&ssum[j], red[0] + red[1] + red[2] + red[3]);
}

// ---- K6: fold all trailing linears into qvec[10] + scalar qc ----
__global__ void k_prep2(const float* __restrict__ ssum, const float* __restrict__ wqa_w,
                        const float* __restrict__ wqa_b, const float* __restrict__ wqr_w,
                        const float* __restrict__ wqr_b, const float* __restrict__ wqact_w,
                        const float* __restrict__ wqact_b,
                        float* __restrict__ qvec, float* __restrict__ qc) {
    int t = threadIdx.x;
    float contrib = 0.f;
    if (t < EMB) {
        float se = wqa_b[t];
        for (int k = 0; k < EMB; ++k) se += ssum[k] * wqa_w[k * EMB + t];
        contrib = se * wqr_w[t] + wqact_b[t] * wqr_w[EMB + t];
        float qv = 0.f;
        for (int j = 0; j < EMB; ++j) qv += wqact_w[t * EMB + j] * wqr_w[EMB + j];
        qvec[t] = qv;
    }
#pragma unroll
    for (int m = 1; m < 64; m <<= 1) contrib += __shfl_xor(contrib, m, 64);
    if (t == 0) qc[0] = contrib + wqr_b[0];
}

// ---- K7: q_vals + copy embeddings to output ----
__global__ void k_out(const float* __restrict__ emb, const float* __restrict__ qvec,
                      const float* __restrict__ qc, float* __restrict__ out) {
    int i = blockIdx.x * blockDim.x + threadIdx.x;
    if (i < N_NODES) {
        float q = qc[0];
        float row[EMB];
#pragma unroll
        for (int j = 0; j < EMB; ++j) {
            row[j] = emb[(size_t)i * EMB + j];
            q += row[j] * qvec[j];
        }
        out[i] = q;
#pragma unroll
        for (int j = 0; j < EMB; ++j) out[N_NODES + (size_t)i * EMB + j] = row[j];
    }
}

extern "C" void kernel_launch(void* const* d_in, const int* in_sizes, int n_in,
                              void* d_out, int out_size, void* d_ws, size_t ws_size,
                              hipStream_t stream) {
    (void)n_in; (void)out_size; (void)ws_size;
    const float* f      = (const float*)d_in[0];
    const float* w      = (const float*)d_in[1];
    const float* A      = (const float*)d_in[2];
    const float* ws_w   = (const float*)d_in[3];
    const float* ws_b   = (const float*)d_in[4];
    const float* wnp_w  = (const float*)d_in[5];
    const float* wnp_b  = (const float*)d_in[6];
    const float* wnw_w  = (const float*)d_in[7];
    const float* wnw_b  = (const float*)d_in[8];
    const float* wew_w  = (const float*)d_in[9];
    const float* wew_b  = (const float*)d_in[10];
    const float* wqr_w  = (const float*)d_in[11];
    const float* wqr_b  = (const float*)d_in[12];
    const float* wqa_w  = (const float*)d_in[13];
    const float* wqa_b  = (const float*)d_in[14];
    const float* wqact_w = (const float*)d_in[15];
    const float* wqact_b = (const float*)d_in[16];
    float* ws  = (float*)d_ws;
    float* out = (float*)d_out;
    const int E = in_sizes[1];

    hipMemsetAsync(ws, 0, 64 * sizeof(float), stream);
    k_edge_sum<<<256, 256, 0, stream>>>(w, E, wew_w, wew_b, ws + WS_SEDGE);
    k_prep1<<<1, 64, 0, stream>>>(ws + WS_SEDGE, wnw_w, wnw_b, ws_b, ws + WS_CBASE);
    k_emb1<<<(N_NODES + 255) / 256, 256, 0, stream>>>(f, ws_w, ws + WS_CBASE, wnp_b,
                                                      ws + WS_EMBA, ws + WS_EMBTA);
    // iter 2: embA -> embB
    k_iter<<<N_NODES / 16, 256, 0, stream>>>(A, ws + WS_EMBTA, f, ws_w, ws + WS_CBASE,
                                             wnp_w, wnp_b, ws + WS_EMBB, ws + WS_EMBTB);
    // iter 3: embB -> embA
    k_iter<<<N_NODES / 16, 256, 0, stream>>>(A, ws + WS_EMBTB, f, ws_w, ws + WS_CBASE,
                                             wnp_w, wnp_b, ws + WS_EMBA, ws + WS_EMBTA);
    k_colsum<<<80, 256, 0, stream>>>(ws + WS_EMBTA, ws + WS_SSUM);
    k_prep2<<<1, 64, 0, stream>>>(ws + WS_SSUM, wqa_w, wqa_b, wqr_w, wqr_b,
                                  wqact_w, wqact_b, ws + WS_QVEC, ws + WS_QVEC + 10);
    k_out<<<(N_NODES + 255) / 256, 256, 0, stream>>>(ws + WS_EMBA, ws + WS_QVEC,
                                                     ws + WS_QVEC + 10, out);
}

// Round 3
// 693.765 us; speedup vs baseline: 1.0636x; 1.0467x over previous
//
#include <hip/hip_runtime.h>

#define N_NODES 10000
#define EMB 10
#define NCHUNK 2500           // N_NODES/4 float4 chunks per row
#define ROWS 4                // rows per block

typedef float f32x4 __attribute__((ext_vector_type(4)));

// workspace float offsets
#define WS_SEDGE 0
#define WS_CBASE 16
#define WS_SSUM  32
#define WS_QVEC  48
#define WS_EMBA  64
#define WS_EMBTA (64 + 100000)
#define WS_EMBB  (64 + 200000)
#define WS_EMBTB (64 + 300000)

// ---- K1: sum_e relu(w_e * wew_w[j] + wew_b[j]) -> sEdge[j] ----
__global__ void k_edge_sum(const float* __restrict__ w, int E,
                           const float* __restrict__ wew_w,
                           const float* __restrict__ wew_b,
                           float* __restrict__ sEdge) {
    __shared__ float red[4][EMB];
    float a[EMB], b[EMB], acc[EMB];
#pragma unroll
    for (int j = 0; j < EMB; ++j) { a[j] = wew_w[j]; b[j] = wew_b[j]; acc[j] = 0.f; }
    for (int e = blockIdx.x * blockDim.x + threadIdx.x; e < E; e += gridDim.x * blockDim.x) {
        float we = w[e];
#pragma unroll
        for (int j = 0; j < EMB; ++j) acc[j] += fmaxf(we * a[j] + b[j], 0.f);
    }
#pragma unroll
    for (int m = 1; m < 64; m <<= 1)
#pragma unroll
        for (int j = 0; j < EMB; ++j) acc[j] += __shfl_xor(acc[j], m, 64);
    int wave = threadIdx.x >> 6, lane = threadIdx.x & 63;
    if (lane == 0)
#pragma unroll
        for (int j = 0; j < EMB; ++j) red[wave][j] = acc[j];
    __syncthreads();
    if (threadIdx.x < EMB)
        atomicAdd(&sEdge[threadIdx.x],
                  red[0][threadIdx.x] + red[1][threadIdx.x] + red[2][threadIdx.x] + red[3][threadIdx.x]);
}

// ---- K2: cbase[j] = ws_b[j] + (sEdge @ wnw_w + wnw_b)[j] ----
__global__ void k_prep1(const float* __restrict__ sEdge, const float* __restrict__ wnw_w,
                        const float* __restrict__ wnw_b, const float* __restrict__ ws_b,
                        float* __restrict__ cbase) {
    int j = threadIdx.x;
    if (j < EMB) {
        float v = wnw_b[j];
        for (int k = 0; k < EMB; ++k) v += sEdge[k] * wnw_w[k * EMB + j];
        cbase[j] = v + ws_b[j];
    }
}

// ---- K3: emb1 (iter 1 closed form, since A@0 == 0) ----
__global__ void k_emb1(const float* __restrict__ f, const float* __restrict__ ws_w,
                       const float* __restrict__ cbase, const float* __restrict__ wnp_b,
                       float* __restrict__ emb, float* __restrict__ embT) {
    int i = blockIdx.x * blockDim.x + threadIdx.x;
    if (i < N_NODES) {
        float fi = f[i];
#pragma unroll
        for (int j = 0; j < EMB; ++j) {
            float v = fmaxf(fi * ws_w[j] + cbase[j] + wnp_b[j], 0.f);
            emb[(size_t)i * EMB + j] = v;
            embT[(size_t)j * N_NODES + i] = v;
        }
    }
}

// ---- K4: fused y = A@emb ; emb' = relu(f*ws_w + cbase + y@wnp_w + wnp_b) ----
// One 4-row tile per block; the 4 waves split the 2500 float4 column-chunks
// (strided by tid). Grid = 2500 blocks -> ~10 blocks/CU, ~40 waves resident
// worth of latency hiding. Per step: 14 loads, 160 lane-FMAs.
__global__ __launch_bounds__(256) void k_iter(
    const float* __restrict__ A, const float* __restrict__ embT_in,
    const float* __restrict__ f, const float* __restrict__ ws_w,
    const float* __restrict__ cbase, const float* __restrict__ wnp_w,
    const float* __restrict__ wnp_b,
    float* __restrict__ emb_out, float* __restrict__ embT_out) {
    const int tid  = threadIdx.x;
    const int wave = tid >> 6;
    const int lane = tid & 63;
    const int r0 = blockIdx.x * ROWS;

    float acc[ROWS][EMB] = {};

    const f32x4* A0 = (const f32x4*)(A + (size_t)(r0 + 0) * N_NODES);
    const f32x4* A1 = (const f32x4*)(A + (size_t)(r0 + 1) * N_NODES);
    const f32x4* A2 = (const f32x4*)(A + (size_t)(r0 + 2) * N_NODES);
    const f32x4* A3 = (const f32x4*)(A + (size_t)(r0 + 3) * N_NODES);

    // 2500 chunks = 9 full 256-chunk steps + 196-chunk tail
#pragma unroll 1
    for (int s = 0; s < 9; ++s) {
        int c = s * 256 + tid;
        f32x4 a0 = __builtin_nontemporal_load(A0 + c);
        f32x4 a1 = __builtin_nontemporal_load(A1 + c);
        f32x4 a2 = __builtin_nontemporal_load(A2 + c);
        f32x4 a3 = __builtin_nontemporal_load(A3 + c);
#pragma unroll
        for (int j = 0; j < EMB; ++j) {
            f32x4 e = ((const f32x4*)(embT_in + (size_t)j * N_NODES))[c];
            acc[0][j] += a0.x * e.x + a0.y * e.y + a0.z * e.z + a0.w * e.w;
            acc[1][j] += a1.x * e.x + a1.y * e.y + a1.z * e.z + a1.w * e.w;
            acc[2][j] += a2.x * e.x + a2.y * e.y + a2.z * e.z + a2.w * e.w;
            acc[3][j] += a3.x * e.x + a3.y * e.y + a3.z * e.z + a3.w * e.w;
        }
    }
    if (tid < NCHUNK - 9 * 256) {  // tail: 196 chunks
        int c = 9 * 256 + tid;
        f32x4 a0 = __builtin_nontemporal_load(A0 + c);
        f32x4 a1 = __builtin_nontemporal_load(A1 + c);
        f32x4 a2 = __builtin_nontemporal_load(A2 + c);
        f32x4 a3 = __builtin_nontemporal_load(A3 + c);
#pragma unroll
        for (int j = 0; j < EMB; ++j) {
            f32x4 e = ((const f32x4*)(embT_in + (size_t)j * N_NODES))[c];
            acc[0][j] += a0.x * e.x + a0.y * e.y + a0.z * e.z + a0.w * e.w;
            acc[1][j] += a1.x * e.x + a1.y * e.y + a1.z * e.z + a1.w * e.w;
            acc[2][j] += a2.x * e.x + a2.y * e.y + a2.z * e.z + a2.w * e.w;
            acc[3][j] += a3.x * e.x + a3.y * e.y + a3.z * e.z + a3.w * e.w;
        }
    }

    // 64-lane butterfly: every lane ends with the wave's full partials
#pragma unroll
    for (int m = 1; m < 64; m <<= 1)
#pragma unroll
        for (int r = 0; r < ROWS; ++r)
#pragma unroll
            for (int j = 0; j < EMB; ++j) acc[r][j] += __shfl_xor(acc[r][j], m, 64);

    // cross-wave combine via LDS
    __shared__ float part[4][ROWS * EMB];
    if (lane == 0)
#pragma unroll
        for (int r = 0; r < ROWS; ++r)
#pragma unroll
            for (int j = 0; j < EMB; ++j) part[wave][r * EMB + j] = acc[r][j];
    __syncthreads();

    if (tid < ROWS * EMB) {
        int r = tid / EMB, j = tid % EMB;
        float v = wnp_b[j];
#pragma unroll
        for (int k = 0; k < EMB; ++k) {
            float yk = part[0][r * EMB + k] + part[1][r * EMB + k] +
                       part[2][r * EMB + k] + part[3][r * EMB + k];
            v += yk * wnp_w[k * EMB + j];
        }
        int i = r0 + r;
        v = fmaxf(f[i] * ws_w[j] + cbase[j] + v, 0.f);
        emb_out[(size_t)i * EMB + j] = v;
        embT_out[(size_t)j * N_NODES + i] = v;
    }
}

// ---- K5: ssum[j] = sum_i emb3[i][j], reading transposed layout ----
__global__ void k_colsum(const float* __restrict__ embT, float* __restrict__ ssum) {
    int j = blockIdx.x % EMB;
    int s = blockIdx.x / EMB;
    float acc = 0.f;
    for (int i = s * blockDim.x + threadIdx.x; i < N_NODES; i += (gridDim.x / EMB) * blockDim.x)
        acc += embT[(size_t)j * N_NODES + i];
#pragma unroll
    for (int m = 1; m < 64; m <<= 1) acc += __shfl_xor(acc, m, 64);
    __shared__ float red[4];
    int wave = threadIdx.x >> 6, lane = threadIdx.x & 63;
    if (lane == 0) red[wave] = acc;
    __syncthreads();
    if (threadIdx.x == 0) atomicAdd(&ssum[j], red[0] + red[1] + red[2] + red[3]);
}

// ---- K6: fold trailing linears into qvec[10] + scalar qc ----
__global__ void k_prep2(const float* __restrict__ ssum, const float* __restrict__ wqa_w,
                        const float* __restrict__ wqa_b, const float* __restrict__ wqr_w,
                        const float* __restrict__ wqr_b, const float* __restrict__ wqact_w,
                        const float* __restrict__ wqact_b,
                        float* __restrict__ qvec, float* __restrict__ qc) {
    int t = threadIdx.x;
    float contrib = 0.f;
    if (t < EMB) {
        float se = wqa_b[t];
        for (int k = 0; k < EMB; ++k) se += ssum[k] * wqa_w[k * EMB + t];
        contrib = se * wqr_w[t] + wqact_b[t] * wqr_w[EMB + t];
        float qv = 0.f;
        for (int j = 0; j < EMB; ++j) qv += wqact_w[t * EMB + j] * wqr_w[EMB + j];
        qvec[t] = qv;
    }
#pragma unroll
    for (int m = 1; m < 64; m <<= 1) contrib += __shfl_xor(contrib, m, 64);
    if (t == 0) qc[0] = contrib + wqr_b[0];
}

// ---- K7: q_vals + copy embeddings to output ----
__global__ void k_out(const float* __restrict__ emb, const float* __restrict__ qvec,
                      const float* __restrict__ qc, float* __restrict__ out) {
    int i = blockIdx.x * blockDim.x + threadIdx.x;
    if (i < N_NODES) {
        float q = qc[0];
        float row[EMB];
#pragma unroll
        for (int j = 0; j < EMB; ++j) {
            row[j] = emb[(size_t)i * EMB + j];
            q += row[j] * qvec[j];
        }
        out[i] = q;
#pragma unroll
        for (int j = 0; j < EMB; ++j) out[N_NODES + (size_t)i * EMB + j] = row[j];
    }
}

extern "C" void kernel_launch(void* const* d_in, const int* in_sizes, int n_in,
                              void* d_out, int out_size, void* d_ws, size_t ws_size,
                              hipStream_t stream) {
    (void)n_in; (void)out_size; (void)ws_size;
    const float* f      = (const float*)d_in[0];
    const float* w      = (const float*)d_in[1];
    const float* A      = (const float*)d_in[2];
    const float* ws_w   = (const float*)d_in[3];
    const float* ws_b   = (const float*)d_in[4];
    const float* wnp_w  = (const float*)d_in[5];
    const float* wnp_b  = (const float*)d_in[6];
    const float* wnw_w  = (const float*)d_in[7];
    const float* wnw_b  = (const float*)d_in[8];
    const float* wew_w  = (const float*)d_in[9];
    const float* wew_b  = (const float*)d_in[10];
    const float* wqr_w  = (const float*)d_in[11];
    const float* wqr_b  = (const float*)d_in[12];
    const float* wqa_w  = (const float*)d_in[13];
    const float* wqa_b  = (const float*)d_in[14];
    const float* wqact_w = (const float*)d_in[15];
    const float* wqact_b = (const float*)d_in[16];
    float* ws  = (float*)d_ws;
    float* out = (float*)d_out;
    const int E = in_sizes[1];

    hipMemsetAsync(ws, 0, 64 * sizeof(float), stream);
    k_edge_sum<<<256, 256, 0, stream>>>(w, E, wew_w, wew_b, ws + WS_SEDGE);
    k_prep1<<<1, 64, 0, stream>>>(ws + WS_SEDGE, wnw_w, wnw_b, ws_b, ws + WS_CBASE);
    k_emb1<<<(N_NODES + 255) / 256, 256, 0, stream>>>(f, ws_w, ws + WS_CBASE, wnp_b,
                                                      ws + WS_EMBA, ws + WS_EMBTA);
    // iter 2: embA -> embB
    k_iter<<<N_NODES / ROWS, 256, 0, stream>>>(A, ws + WS_EMBTA, f, ws_w, ws + WS_CBASE,
                                               wnp_w, wnp_b, ws + WS_EMBB, ws + WS_EMBTB);
    // iter 3: embB -> embA
    k_iter<<<N_NODES / ROWS, 256, 0, stream>>>(A, ws + WS_EMBTB, f, ws_w, ws + WS_CBASE,
                                               wnp_w, wnp_b, ws + WS_EMBA, ws + WS_EMBTA);
    k_colsum<<<80, 256, 0, stream>>>(ws + WS_EMBTA, ws + WS_SSUM);
    k_prep2<<<1, 64, 0, stream>>>(ws + WS_SSUM, wqa_w, wqa_b, wqr_w, wqr_b,
                                  wqact_w, wqact_b, ws + WS_QVEC, ws + WS_QVEC + 10);
    k_out<<<(N_NODES + 255) / 256, 256, 0, stream>>>(ws + WS_EMBA, ws + WS_QVEC,
                                                     ws + WS_QVEC + 10, out);
}